// Round 4
// baseline (531.355 us; speedup 1.0000x reference)
//
#include <hip/hip_runtime.h>
#include <math.h>

// Problem constants (from reference): B=4, H=16, L=1024, scales ws={2,4,8}, HIDDEN=32
#define L_DIM 1024
#define BH 64   // B*H

// native vector type — __builtin_nontemporal_load requires scalar/native-vector pointee
typedef float floatx4 __attribute__((ext_vector_type(4)));

// ---------------------------------------------------------------------------
// Fully fused kernel. Grid: BH*128 = 8192 blocks x 512 threads.
// Block = one 8-row group (ws=8 window) of one (b,h); all window boundaries
// for ws={2,4,8} align at multiples of 8, so the block is self-contained.
//
// Phase 1: 8 waves x 2 rows each (waves 0-3: attn_1 rows 0..7, waves 4-7:
//          attn_2 rows 0..7). Per-row stats (mean, std ddof=1, max, min) via
//          float4 nontemporal loads + 64-lane butterfly; lane 0 -> LDS.
// Phase 2: waves 0..2 compute the scale-s MLP (s = wave id, uniform ->
//          weights via scalar K$ loads). Lane = window index (4/2/1 used).
// Phase 3: threads 0..7 write the softmax-weighted combine (one float per
//          output row, 32 B coalesced per block; 256 KB total).
// ---------------------------------------------------------------------------
__global__ __launch_bounds__(512) void fused_gate_kernel(
    const float* __restrict__ a1, const float* __restrict__ a2,
    const float* __restrict__ W1, const float* __restrict__ b1,
    const float* __restrict__ W2, const float* __restrict__ b2,
    const float* __restrict__ W3, const float* __restrict__ b3,
    const float* __restrict__ sw,
    float* __restrict__ out)
{
    __shared__ float4 sh_stats[16];  // [t*8 + local_row]
    __shared__ float  sh_alpha[8];   // [0..3]=ws2 windows, [4..5]=ws4, [6]=ws8

    const int tid  = threadIdx.x;
    const int w    = tid >> 6;
    const int lane = tid & 63;
    const int bh   = blockIdx.x >> 7;
    const int row0 = (blockIdx.x & 127) << 3;   // local 8-row group base

    // ---------------- phase 1: row stats (2 rows per wave) ----------------
    const int t  = w >> 2;
    const int pr = (w & 3) << 1;   // local row pair base: 0,2,4,6
    const float* __restrict__ src = t ? a2 : a1;
    const floatx4* __restrict__ p =
        (const floatx4*)(src + ((size_t)bh * L_DIM + row0 + pr) * L_DIM);
    // row pr -> p[0..255], row pr+1 -> p[256..511]

    float s0 = 0.f, q0 = 0.f, mx0 = -INFINITY, mn0 = INFINITY;
    float s1 = 0.f, q1 = 0.f, mx1 = -INFINITY, mn1 = INFINITY;
#pragma unroll
    for (int c = 0; c < 4; ++c) {
        floatx4 v = __builtin_nontemporal_load(&p[(c << 6) + lane]);
        floatx4 u = __builtin_nontemporal_load(&p[256 + (c << 6) + lane]);
        s0 += v.x + v.y + v.z + v.w;
        q0 += v.x * v.x + v.y * v.y + v.z * v.z + v.w * v.w;
        mx0 = fmaxf(mx0, fmaxf(fmaxf(v.x, v.y), fmaxf(v.z, v.w)));
        mn0 = fminf(mn0, fminf(fminf(v.x, v.y), fminf(v.z, v.w)));
        s1 += u.x + u.y + u.z + u.w;
        q1 += u.x * u.x + u.y * u.y + u.z * u.z + u.w * u.w;
        mx1 = fmaxf(mx1, fmaxf(fmaxf(u.x, u.y), fmaxf(u.z, u.w)));
        mn1 = fminf(mn1, fminf(fminf(u.x, u.y), fminf(u.z, u.w)));
    }
#pragma unroll
    for (int off = 32; off > 0; off >>= 1) {
        s0 += __shfl_xor(s0, off, 64);  q0 += __shfl_xor(q0, off, 64);
        mx0 = fmaxf(mx0, __shfl_xor(mx0, off, 64));
        mn0 = fminf(mn0, __shfl_xor(mn0, off, 64));
        s1 += __shfl_xor(s1, off, 64);  q1 += __shfl_xor(q1, off, 64);
        mx1 = fmaxf(mx1, __shfl_xor(mx1, off, 64));
        mn1 = fminf(mn1, __shfl_xor(mn1, off, 64));
    }
    if (lane == 0) {
        const float invL  = 1.0f / (float)L_DIM;
        const float invN1 = 1.0f / (float)(L_DIM - 1);   // ddof=1
        float4 o0, o1;
        o0.x = s0 * invL;
        o0.y = sqrtf(fmaxf((q0 - s0 * s0 * invL) * invN1, 0.f));
        o0.z = mx0; o0.w = mn0;
        o1.x = s1 * invL;
        o1.y = sqrtf(fmaxf((q1 - s1 * s1 * invL) * invN1, 0.f));
        o1.z = mx1; o1.w = mn1;
        sh_stats[t * 8 + pr]     = o0;
        sh_stats[t * 8 + pr + 1] = o1;
    }
    __syncthreads();

    // ---------------- phase 2: MLPs (waves 0..2, s = wave id) ----------------
    if (w < 3) {
        const int ws = 2 << w;         // 2,4,8
        const int nw = 4 >> w;         // 4,2,1 windows in this 8-row group
        const int wi = (lane < nw) ? lane : 0;   // clamp idle lanes (no OOB)

        // s is wave-uniform -> pin to SGPR so weight reads are s_load (K$).
        const int su = __builtin_amdgcn_readfirstlane(w);
        const float* __restrict__ W1p = W1 + su * 256;   // [32][8]
        const float* __restrict__ b1p = b1 + su * 32;
        const float* __restrict__ W2p = W2 + su * 512;   // [16][32]
        const float* __restrict__ b2p = b2 + su * 16;
        const float* __restrict__ W3p = W3 + su * 16;    // [1][16]
        const float  b3v = b3[su];

        float g[8] = {0.f, 0.f, 0.f, 0.f, 0.f, 0.f, 0.f, 0.f};
        for (int j = 0; j < ws; ++j) {
            float4 v1 = sh_stats[wi * ws + j];
            float4 v2 = sh_stats[8 + wi * ws + j];
            g[0] += v1.x; g[1] += v1.y; g[2] += v1.z; g[3] += v1.w;
            g[4] += v2.x; g[5] += v2.y; g[6] += v2.z; g[7] += v2.w;
        }
        const float inv = 1.0f / (float)ws;
#pragma unroll
        for (int k = 0; k < 8; ++k) g[k] *= inv;

        // MLP 8 -> 32 -> 16 -> 1 (relu, relu, sigmoid)
        float h1[32];
#pragma unroll
        for (int o = 0; o < 32; ++o) {
            float acc = b1p[o];
#pragma unroll
            for (int f = 0; f < 8; ++f) acc += W1p[o * 8 + f] * g[f];
            h1[o] = fmaxf(acc, 0.f);
        }
        float h2[16];
#pragma unroll
        for (int o = 0; o < 16; ++o) {
            float acc = b2p[o];
#pragma unroll
            for (int f = 0; f < 32; ++f) acc += W2p[o * 32 + f] * h1[f];
            h2[o] = fmaxf(acc, 0.f);
        }
        float acc = b3v;
#pragma unroll
        for (int f = 0; f < 16; ++f) acc += W3p[f] * h2[f];

        if (lane < nw) {
            const int aoff = (w == 0) ? 0 : ((w == 1) ? 4 : 6);
            sh_alpha[aoff + lane] = 1.0f / (1.0f + expf(-acc));
        }
    }
    __syncthreads();

    // ---------------- phase 3: combine + write (threads 0..7) ----------------
    if (tid < 8) {
        const float x0 = sw[0], x1 = sw[1], x2 = sw[2];
        const float m  = fmaxf(x0, fmaxf(x1, x2));
        const float e0 = expf(x0 - m), e1 = expf(x1 - m), e2 = expf(x2 - m);
        const float ei = 1.0f / (e0 + e1 + e2);
        out[(size_t)bh * L_DIM + row0 + tid] =
              (e0 * ei) * sh_alpha[tid >> 1]
            + (e1 * ei) * sh_alpha[4 + (tid >> 2)]
            + (e2 * ei) * sh_alpha[6];
    }
}

extern "C" void kernel_launch(void* const* d_in, const int* in_sizes, int n_in,
                              void* d_out, int out_size, void* d_ws, size_t ws_size,
                              hipStream_t stream) {
    const float* attn1 = (const float*)d_in[0];
    const float* attn2 = (const float*)d_in[1];
    const float* W1 = (const float*)d_in[2];
    const float* b1 = (const float*)d_in[3];
    const float* W2 = (const float*)d_in[4];
    const float* b2 = (const float*)d_in[5];
    const float* W3 = (const float*)d_in[6];
    const float* b3 = (const float*)d_in[7];
    const float* sw = (const float*)d_in[8];
    float* out = (float*)d_out;

    // one block per 8-row group per (b,h); d_ws unused
    fused_gate_kernel<<<BH * 128, 512, 0, stream>>>(
        attn1, attn2, W1, b1, W2, b2, W3, b3, sw, out);
}